// Round 11
// baseline (18892.517 us; speedup 1.0000x reference)
//
#include <hip/hip_runtime.h>
#include <stdint.h>

typedef _Float16 f16;
typedef _Float16 half8 __attribute__((ext_vector_type(8)));
typedef float f32x4 __attribute__((ext_vector_type(4)));
typedef unsigned long long u64;

#define T_SEQ 1024
#define NWG 512
#define FS 8                  // flag stride in u32 -> 32B
#define HPLANE 16384          // f16 elements per h plane
#define ESLOT 24576           // f16 elements per e slot

// ws byte layout (memset [0,9216) each launch)
#define OFF_FAL 0             // fAL[64] local island-A flags
#define OFF_FBL 2048          // fBL[64] local island-B flags
#define OFF_FAG 4096          // fAG[64] agent copies (A)
#define OFF_FBG 6144          // fBG[64] agent copies (B)
#define OFF_FP  8192          // fP[8] producer flags
#define OFF_CLAIM 8448        // claim[8] (stride 32B)
#define OFF_WINA 8704
#define OFF_WINB 8708
#define OFF_PRODC 8712
#define WS_H0L 16384          // 2 planes x 32768B (island-A local)
#define WS_H1L (WS_H0L + 65536)   // 2 planes (island-B local)
#define WS_H0G (WS_H1L + 65536)   // 4 planes (agent copy for L1)
#define WS_E   (WS_H0G + 131072)  // 3 slots x 49152B  -> end 425984 B

static __device__ __forceinline__ void drain_vm() {
    asm volatile("s_waitcnt vmcnt(0)" ::: "memory");
    __builtin_amdgcn_sched_barrier(0);
}
static __device__ __forceinline__ void ld16_ag(half8* d, const f16* p) {   // L3-coherent
    asm volatile("global_load_dwordx4 %0, %1, off sc0 sc1" : "=v"(*d) : "v"(p) : "memory");
}
static __device__ __forceinline__ void ld16_l2(half8* d, const f16* p) {   // XCD-L2
    asm volatile("global_load_dwordx4 %0, %1, off sc0" : "=v"(*d) : "v"(p) : "memory");
}

static __device__ __forceinline__ void pollA(const uint32_t* flags, int n,
                                             uint32_t need, int lane) {
    const uint32_t* p = flags + (size_t)(lane < n ? lane : 0) * FS;
    while (true) {
        uint32_t v = __hip_atomic_load(p, __ATOMIC_RELAXED, __HIP_MEMORY_SCOPE_AGENT);
        if (__all(v >= need)) break;
        __builtin_amdgcn_s_sleep(1);
    }
    __builtin_amdgcn_sched_barrier(0);
}
// island-local poll (sc0/L2) with agent fallback every 64th iter (hang-proof)
static __device__ __forceinline__ void pollI(const uint32_t* loc, const uint32_t* agt,
                                             uint32_t need, int lane) {
    const uint32_t* pl = loc + (size_t)lane * FS;
    const uint32_t* pa = agt + (size_t)lane * FS;
    int it = 0;
    while (true) {
        uint32_t v;
        if ((++it & 63) == 0) {
            v = __hip_atomic_load(pa, __ATOMIC_RELAXED, __HIP_MEMORY_SCOPE_AGENT);
        } else {
            asm volatile("global_load_dword %0, %1, off sc0\n\ts_waitcnt vmcnt(0)"
                         : "=v"(v) : "v"(pl) : "memory");
        }
        if (__all(v >= need)) break;
        __builtin_amdgcn_s_sleep(1);
    }
    __builtin_amdgcn_sched_barrier(0);
}

__global__ void __launch_bounds__(256, 2)
lstm_fused(const int* __restrict__ x, const float* __restrict__ emb,
           const float* __restrict__ w_ih0, const float* __restrict__ w_hh0,
           const float* __restrict__ b_ih0, const float* __restrict__ b_hh0,
           const float* __restrict__ w_ih1, const float* __restrict__ w_hh1,
           const float* __restrict__ b_ih1, const float* __restrict__ b_hh1,
           const float* __restrict__ fc_w, const float* __restrict__ fc_b,
           float* __restrict__ out, uint8_t* __restrict__ ws)
{
    const int tid  = threadIdx.x;
    const int lane = tid & 63;
    const int wave = tid >> 6;
    const int mtile = wave >> 1;
    const int ntile = wave & 1;
    const int r8   = lane & 15;
    const int kgb  = lane >> 4;
    const int arow = mtile * 16 + r8;
    const int tb = tid >> 3, tj = tid & 7;

    uint32_t* fAL = (uint32_t*)(ws + OFF_FAL);
    uint32_t* fBL = (uint32_t*)(ws + OFF_FBL);
    uint32_t* fAG = (uint32_t*)(ws + OFF_FAG);
    uint32_t* fBG = (uint32_t*)(ws + OFF_FBG);
    uint32_t* fP  = (uint32_t*)(ws + OFF_FP);
    f16* h0L = (f16*)(ws + WS_H0L);
    f16* h1L = (f16*)(ws + WS_H1L);
    f16* h0G = (f16*)(ws + WS_H0G);
    f16* er  = (f16*)(ws + WS_E);

    __shared__ half8 wlds[2 * 32 * 64];   // 65536B: LDS-resident weight frags
    __shared__ float accs[32][33];
    __shared__ float bias_lds[32];
    __shared__ f16   hsh[32][8];
    __shared__ uint32_t role_sh[2];

    // ---------------- role claim (XCD islands) ----------------
    uint32_t xcc;
    asm("s_getreg_b32 %0, hwreg(HW_REG_XCC_ID)" : "=s"(xcc));
    xcc &= 7u;
    if (tid == 0) {
        uint32_t* claimc = (uint32_t*)(ws + OFF_CLAIM) + (size_t)xcc * 8;
        uint32_t* winA = (uint32_t*)(ws + OFF_WINA);
        uint32_t* winB = (uint32_t*)(ws + OFF_WINB);
        uint32_t* prodc = (uint32_t*)(ws + OFF_PRODC);
        uint32_t idx = __hip_atomic_fetch_add(claimc, 1u, __ATOMIC_RELAXED,
                                              __HIP_MEMORY_SCOPE_AGENT);
        if (idx == 63u) {   // 64th claimant nominates its XCD
            uint32_t exp = 0u;
            if (!__hip_atomic_compare_exchange_strong(winA, &exp, xcc + 1u,
                    __ATOMIC_RELAXED, __ATOMIC_RELAXED, __HIP_MEMORY_SCOPE_AGENT)) {
                exp = 0u;
                __hip_atomic_compare_exchange_strong(winB, &exp, xcc + 1u,
                    __ATOMIC_RELAXED, __ATOMIC_RELAXED, __HIP_MEMORY_SCOPE_AGENT);
            }
        }
        uint32_t wB;
        while ((wB = __hip_atomic_load(winB, __ATOMIC_RELAXED,
                                       __HIP_MEMORY_SCOPE_AGENT)) == 0u)
            __builtin_amdgcn_s_sleep(8);
        uint32_t wA = __hip_atomic_load(winA, __ATOMIC_RELAXED, __HIP_MEMORY_SCOPE_AGENT);
        uint32_t role, rid = idx;
        if (xcc + 1u == wA && idx < 64u)      role = 0u;   // L0 island
        else if (xcc + 1u == wB && idx < 64u) role = 1u;   // L1 island
        else if (xcc + 1u != wA && xcc + 1u != wB) {       // producers off-island
            uint32_t p = __hip_atomic_fetch_add(prodc, 1u, __ATOMIC_RELAXED,
                                                __HIP_MEMORY_SCOPE_AGENT);
            role = (p < 8u) ? 2u : 3u; rid = p;
        } else role = 3u;
        role_sh[0] = role; role_sh[1] = rid;
    }
    __syncthreads();
    const uint32_t role = role_sh[0];
    const uint32_t rid  = role_sh[1];
    if (role == 3u) return;

    // ---------------- e-producers (8, agent scope, 3-deep ring) ----------------
    if (role == 2u) {
        const int p = (int)rid;        // batch rows 4p..4p+3
        auto gather = [&](int t, int slot) {
#pragma unroll
            for (int rr = 0; rr < 2; ++rr) {
                int idx2 = rr * 256 + tid;
                if (idx2 < 384) {
                    int bl = idx2 / 96, seg = idx2 % 96, k0 = seg * 8;
                    int b = p * 4 + bl;
                    int tok = x[b * T_SEQ + t];
                    const float* src = emb + (size_t)tok * 768 + k0;
                    float4 v0 = ((const float4*)src)[0];
                    float4 v1 = ((const float4*)src)[1];
                    union { half8 h; u64 q[2]; } u;
                    u.h[0] = (f16)v0.x; u.h[1] = (f16)v0.y; u.h[2] = (f16)v0.z; u.h[3] = (f16)v0.w;
                    u.h[4] = (f16)v1.x; u.h[5] = (f16)v1.y; u.h[6] = (f16)v1.z; u.h[7] = (f16)v1.w;
                    u64* dst = (u64*)(er + (size_t)slot * ESLOT + ((size_t)seg * 32 + b) * 8);
                    __hip_atomic_store(dst,     u.q[0], __ATOMIC_RELAXED, __HIP_MEMORY_SCOPE_AGENT);
                    __hip_atomic_store(dst + 1, u.q[1], __ATOMIC_RELAXED, __HIP_MEMORY_SCOPE_AGENT);
                }
            }
        };
        gather(0, 0); gather(1, 1); gather(2, 2);
        asm volatile("s_waitcnt vmcnt(0)" ::: "memory");
        __syncthreads();
        if (tid == 0)
            __hip_atomic_store(fP + rid * FS, 3u, __ATOMIC_RELAXED, __HIP_MEMORY_SCOPE_AGENT);
        int gs = 0;                    // slot of g (g=3 -> slot 0)
        for (int g = 3; g < T_SEQ; ++g) {
            pollA(fAG, 64, (uint32_t)(g - 1), lane);   // L0 done round g-3 (slot free)
            gather(g, gs);
            asm volatile("s_waitcnt vmcnt(0)" ::: "memory");
            __syncthreads();
            if (tid == 0)
                __hip_atomic_store(fP + rid * FS, (uint32_t)(g + 1),
                                   __ATOMIC_RELAXED, __HIP_MEMORY_SCOPE_AGENT);
            gs = (gs == 2) ? 0 : gs + 1;
        }
        return;
    }

    // ---------------- island wgs ----------------
    const bool isL0 = (role == 0u);
    const int j0 = (int)rid * 8;
    const int nrow = ((ntile * 2 + (r8 >> 3)) << 9) + j0 + (r8 & 7);

    // LDS weights: L0: [2][32][64] = e-part kc0..23 + W_hh0 khh8..15 (kc24..31)
    //              L1: [2][24][64] = W_ih1 kc0..15 + W_hh1 khh8..15 (kc16..23)
    if (wave < 2) {
        if (isL0) {
            for (int kc = 0; kc < 32; ++kc) {
                const float* src = (kc < 24)
                    ? (w_ih0 + (size_t)nrow * 768 + kc * 32 + kgb * 8)
                    : (w_hh0 + (size_t)nrow * 512 + (kc - 16) * 32 + kgb * 8);
                half8 v;
#pragma unroll
                for (int e = 0; e < 8; ++e) v[e] = (f16)src[e];
                wlds[(ntile * 32 + kc) * 64 + lane] = v;
            }
        } else {
            for (int kc = 0; kc < 24; ++kc) {
                const float* src = (kc < 16)
                    ? (w_ih1 + (size_t)nrow * 512 + kc * 32 + kgb * 8)
                    : (w_hh1 + (size_t)nrow * 512 + (kc - 8) * 32 + kgb * 8);
                half8 v;
#pragma unroll
                for (int e = 0; e < 8; ++e) v[e] = (f16)src[e];
                wlds[(ntile * 24 + kc) * 64 + lane] = v;
            }
        }
    }
    // pinned W_hh khh 0..7 (32 VGPR)
    half8 breg[8];
    {
        const float* wsrc = isL0 ? w_hh0 : w_hh1;
#pragma unroll
        for (int kc = 0; kc < 8; ++kc) {
            const float* src = wsrc + (size_t)nrow * 512 + kc * 32 + kgb * 8;
            half8 v;
#pragma unroll
            for (int e = 0; e < 8; ++e) v[e] = (f16)src[e];
            breg[kc] = v;
        }
#pragma unroll
        for (int kc = 0; kc < 8; ++kc) asm volatile("" : "+v"(breg[kc]));
    }
    if (tid < 32) {
        int n2 = ((tid >> 3) << 9) + j0 + (tid & 7);
        bias_lds[tid] = isL0 ? (b_ih0[n2] + b_hh0[n2]) : (b_ih1[n2] + b_hh1[n2]);
    }
    // zero own slice of local plane 1 (h_{-1})
    if (tid < 32) {
        u64* z = (u64*)((isL0 ? h0L : h1L) + 1 * HPLANE) + (size_t)rid * 32 + tid;
        *z = 0ULL;
    }
    if (wave == 0) drain_vm();
    __syncthreads();
    if (tid == 0)
        ((volatile uint32_t*)(isL0 ? fAL : fBL))[rid * FS] = isL0 ? 1u : 2u;
    if (tid == 64)
        __hip_atomic_store((isL0 ? fAG : fBG) + rid * FS, isL0 ? 1u : 2u,
                           __ATOMIC_RELAXED, __HIP_MEMORY_SCOPE_AGENT);

    float cst = 0.f;
    const int crow0 = mtile * 16 + (lane >> 4) * 4;
    const int ccol  = ntile * 16 + r8;

    if (isL0) {
        // =================== L0 island ===================
        int es = 0;
        for (int s = 0; s < T_SEQ; ++s) {
            pollI(fAL, fAG, (uint32_t)(s + 1), lane);                    // sibs done s-1
            pollA(fBG, 64, (s >= 2) ? (uint32_t)(s - 1) : 1u, lane);     // h0G plane free
            pollA(fP, 8, (uint32_t)(s + 1), lane);                       // e_s ready
            const f16* pe = er + (size_t)es * ESLOT;
            const f16* ph = h0L + (size_t)((s + 1) & 1) * HPLANE;        // h0_{s-1}
            half8 ean[24], hf[16];
#pragma unroll
            for (int kc = 0; kc < 24; ++kc)
                ld16_ag(&ean[kc], pe + (((size_t)(kc * 4 + kgb) * 32 + arow) << 3));
#pragma unroll
            for (int kc = 0; kc < 16; ++kc)
                ld16_l2(&hf[kc], ph + (((size_t)(kc * 4 + kgb) * 32 + arow) << 3));
            drain_vm();
            f32x4 acc0 = {0,0,0,0}, acc1 = {0,0,0,0};
#pragma unroll
            for (int kc = 0; kc < 24; ++kc) {
                half8 bw = wlds[(ntile * 32 + kc) * 64 + lane];
                if (kc & 1) acc1 = __builtin_amdgcn_mfma_f32_16x16x32_f16(ean[kc], bw, acc1, 0, 0, 0);
                else        acc0 = __builtin_amdgcn_mfma_f32_16x16x32_f16(ean[kc], bw, acc0, 0, 0, 0);
            }
#pragma unroll
            for (int kc = 0; kc < 8; ++kc) {
                if (kc & 1) acc1 = __builtin_amdgcn_mfma_f32_16x16x32_f16(hf[kc], breg[kc], acc1, 0, 0, 0);
                else        acc0 = __builtin_amdgcn_mfma_f32_16x16x32_f16(hf[kc], breg[kc], acc0, 0, 0, 0);
            }
#pragma unroll
            for (int kc = 8; kc < 16; ++kc) {
                half8 bw = wlds[(ntile * 32 + 16 + kc) * 64 + lane];
                if (kc & 1) acc1 = __builtin_amdgcn_mfma_f32_16x16x32_f16(hf[kc], bw, acc1, 0, 0, 0);
                else        acc0 = __builtin_amdgcn_mfma_f32_16x16x32_f16(hf[kc], bw, acc0, 0, 0, 0);
            }
            {
                f32x4 accv = acc0 + acc1;
#pragma unroll
                for (int q = 0; q < 4; ++q) accs[crow0 + q][ccol] = accv[q];
            }
            __syncthreads();
            {
                float gi = accs[tb][tj]      + bias_lds[tj];
                float gf = accs[tb][8 + tj]  + bias_lds[8 + tj];
                float gg = accs[tb][16 + tj] + bias_lds[16 + tj];
                float go = accs[tb][24 + tj] + bias_lds[24 + tj];
                float si = __builtin_amdgcn_rcpf(1.f + __expf(-gi));
                float sf = __builtin_amdgcn_rcpf(1.f + __expf(-gf));
                float so = __builtin_amdgcn_rcpf(1.f + __expf(-go));
                float tg = 1.f - 2.f * __builtin_amdgcn_rcpf(__expf(2.f * gg) + 1.f);
                cst = sf * cst + si * tg;
                float hv = so * (1.f - 2.f * __builtin_amdgcn_rcpf(__expf(2.f * cst) + 1.f));
                hsh[tb][tj] = (f16)hv;
            }
            __syncthreads();
            if (wave == 0) {           // local publish (critical path)
                if (lane < 32) {
                    u64* dst = (u64*)(h0L + (size_t)(s & 1) * HPLANE) + ((size_t)rid * 32 + lane) * 2;
                    const u64* sp = (const u64*)hsh + lane * 2;
                    dst[0] = sp[0]; dst[1] = sp[1];
                }
                drain_vm();
                if (lane == 0)
                    ((volatile uint32_t*)fAL)[rid * FS] = (uint32_t)(s + 2);
            } else if (wave == 1) {    // global publish for L1 (lag-tolerant)
                if (lane < 32) {
                    u64* dst = (u64*)(h0G + (size_t)(s & 3) * HPLANE) + ((size_t)rid * 32 + lane) * 2;
                    const u64* sp = (const u64*)hsh + lane * 2;
                    __hip_atomic_store(dst,     sp[0], __ATOMIC_RELAXED, __HIP_MEMORY_SCOPE_AGENT);
                    __hip_atomic_store(dst + 1, sp[1], __ATOMIC_RELAXED, __HIP_MEMORY_SCOPE_AGENT);
                }
                drain_vm();
                if (lane == 0)
                    __hip_atomic_store(fAG + rid * FS, (uint32_t)(s + 2),
                                       __ATOMIC_RELAXED, __HIP_MEMORY_SCOPE_AGENT);
            }
            es = (es == 2) ? 0 : es + 1;
        }
        return;
    }

    // =================== L1 island ===================
    for (int s = 1; s <= T_SEQ; ++s) {
        pollI(fBL, fBG, (uint32_t)(s + 1), lane);   // sibs done s-1
        pollA(fAG, 64, (uint32_t)(s + 1), lane);    // h0_{s-1} published
        const f16* pg = h0G + (size_t)((s - 1) & 3) * HPLANE;   // h0_{s-1}
        const f16* ph = h1L + (size_t)(s & 1) * HPLANE;         // h1_{s-2}
        half8 ag[16], hf[16];
#pragma unroll
        for (int kc = 0; kc < 16; ++kc)
            ld16_ag(&ag[kc], pg + (((size_t)(kc * 4 + kgb) * 32 + arow) << 3));
#pragma unroll
        for (int kc = 0; kc < 16; ++kc)
            ld16_l2(&hf[kc], ph + (((size_t)(kc * 4 + kgb) * 32 + arow) << 3));
        drain_vm();
        f32x4 acc0 = {0,0,0,0}, acc1 = {0,0,0,0};
#pragma unroll
        for (int kc = 0; kc < 16; ++kc) {
            half8 bw = wlds[(ntile * 24 + kc) * 64 + lane];
            if (kc & 1) acc1 = __builtin_amdgcn_mfma_f32_16x16x32_f16(ag[kc], bw, acc1, 0, 0, 0);
            else        acc0 = __builtin_amdgcn_mfma_f32_16x16x32_f16(ag[kc], bw, acc0, 0, 0, 0);
        }
#pragma unroll
        for (int kc = 0; kc < 8; ++kc) {
            if (kc & 1) acc1 = __builtin_amdgcn_mfma_f32_16x16x32_f16(hf[kc], breg[kc], acc1, 0, 0, 0);
            else        acc0 = __builtin_amdgcn_mfma_f32_16x16x32_f16(hf[kc], breg[kc], acc0, 0, 0, 0);
        }
#pragma unroll
        for (int kc = 8; kc < 16; ++kc) {
            half8 bw = wlds[(ntile * 24 + 8 + kc) * 64 + lane];
            if (kc & 1) acc1 = __builtin_amdgcn_mfma_f32_16x16x32_f16(hf[kc], bw, acc1, 0, 0, 0);
            else        acc0 = __builtin_amdgcn_mfma_f32_16x16x32_f16(hf[kc], bw, acc0, 0, 0, 0);
        }
        {
            f32x4 accv = acc0 + acc1;
#pragma unroll
            for (int q = 0; q < 4; ++q) accs[crow0 + q][ccol] = accv[q];
        }
        __syncthreads();
        {
            float gi = accs[tb][tj]      + bias_lds[tj];
            float gf = accs[tb][8 + tj]  + bias_lds[8 + tj];
            float gg = accs[tb][16 + tj] + bias_lds[16 + tj];
            float go = accs[tb][24 + tj] + bias_lds[24 + tj];
            float si = __builtin_amdgcn_rcpf(1.f + __expf(-gi));
            float sf = __builtin_amdgcn_rcpf(1.f + __expf(-gf));
            float so = __builtin_amdgcn_rcpf(1.f + __expf(-go));
            float tg = 1.f - 2.f * __builtin_amdgcn_rcpf(__expf(2.f * gg) + 1.f);
            cst = sf * cst + si * tg;
            float hv = so * (1.f - 2.f * __builtin_amdgcn_rcpf(__expf(2.f * cst) + 1.f));
            hsh[tb][tj] = (f16)hv;
        }
        __syncthreads();
        if (wave == 0) {
            if (lane < 32) {
                u64* dst = (u64*)(h1L + (size_t)((s + 1) & 1) * HPLANE) + ((size_t)rid * 32 + lane) * 2;
                const u64* sp = (const u64*)hsh + lane * 2;
                dst[0] = sp[0]; dst[1] = sp[1];
            }
            drain_vm();
            if (lane == 0)
                ((volatile uint32_t*)fBL)[rid * FS] = (uint32_t)(s + 2);
        } else if (wave == 1 && lane == 0) {
            __hip_atomic_store(fBG + rid * FS, (uint32_t)(s + 2),
                               __ATOMIC_RELAXED, __HIP_MEMORY_SCOPE_AGENT);
        }
    }

    // ---------- FC epilogue (island-B wg 0): h2 = h1_{1023} = local plane 1 ----------
    if (rid == 0) {
        pollI(fBL, fBG, (uint32_t)(T_SEQ + 2), lane);
        f16* stg = (f16*)wlds;
        const f16* h2 = h1L + 1 * HPLANE;
        for (int i = tid; i < 2048; i += 256) {
            half8 v;
            asm volatile("global_load_dwordx4 %0, %1, off sc0\n\ts_waitcnt vmcnt(0)"
                         : "=v"(v) : "v"(h2 + (size_t)i * 8) : "memory");
            *(half8*)(stg + (size_t)i * 8) = v;
        }
        __syncthreads();
        if (tid < 160) {
            int b = tid / 5, n = tid % 5;
            float fsum = fc_b[n];
#pragma unroll 8
            for (int j = 0; j < 512; ++j)
                fsum += (float)stg[((j >> 3) * 32 + b) * 8 + (j & 7)] * fc_w[n * 512 + j];
            out[b * 5 + n] = fsum;
        }
    }
}

extern "C" void kernel_launch(void* const* d_in, const int* in_sizes, int n_in,
                              void* d_out, int out_size, void* d_ws, size_t ws_size,
                              hipStream_t stream) {
    (void)in_sizes; (void)n_in; (void)out_size; (void)ws_size;
    hipMemsetAsync(d_ws, 0, 9216, stream);   // flags + claim state start at 0
    lstm_fused<<<dim3(NWG), dim3(256), 0, stream>>>(
        (const int*)d_in[0],  (const float*)d_in[1],
        (const float*)d_in[2], (const float*)d_in[3],
        (const float*)d_in[4], (const float*)d_in[5],
        (const float*)d_in[6], (const float*)d_in[7],
        (const float*)d_in[8], (const float*)d_in[9],
        (const float*)d_in[10], (const float*)d_in[11],
        (float*)d_out, (uint8_t*)d_ws);
}

// Round 12
// 8740.479 us; speedup vs baseline: 2.1615x; 2.1615x over previous
//
#include <hip/hip_runtime.h>
#include <stdint.h>

typedef _Float16 f16;
typedef _Float16 half8 __attribute__((ext_vector_type(8)));
typedef float f32x4 __attribute__((ext_vector_type(4)));
typedef unsigned long long u64;

#define T_SEQ 1024
#define NWG 136            // 64 L0 + 64 L1 + 8 e-producers
#define FS 8               // flag stride in u32 -> 32B
#define D0 6               // h0 ring depth
#define D1 4               // h1 ring depth
#define DE 3               // e ring depth
#define HPLANE 16384       // f16 per h plane (32 KB)
#define ESLOT 24576        // f16 per e slot (48 KB)

// ws layout (memset [0,8192) each launch)
#define OFF_FA 0                       // fA[64]: L0 progress (producers+startup+L1-lag ref)
#define OFF_FB 2048                    // fB[64]: L1 progress (L0 anti-dep, lag tol 3)
#define OFF_FP 4096                    // fP[8]:  producer progress
#define WS_H0 8192                     // 6 planes x 32768 B
#define WS_H1 (WS_H0 + D0 * 32768)    // 4 planes
#define WS_E  (WS_H1 + D1 * 32768)    // 3 slots x 49152 B -> end 483328
#define POISON 0x7FFF7FFF7FFF7FFFULL

static __device__ __forceinline__ u64 ld64(const u64* p) {
    return __hip_atomic_load(p, __ATOMIC_RELAXED, __HIP_MEMORY_SCOPE_AGENT);
}
static __device__ __forceinline__ void st64(u64* p, u64 v) {
    __hip_atomic_store(p, v, __ATOMIC_RELAXED, __HIP_MEMORY_SCOPE_AGENT);
}
static __device__ __forceinline__ uint32_t ld32(const uint32_t* p) {
    return __hip_atomic_load(p, __ATOMIC_RELAXED, __HIP_MEMORY_SCOPE_AGENT);
}
static __device__ __forceinline__ void st32(uint32_t* p, uint32_t v) {
    __hip_atomic_store(p, v, __ATOMIC_RELAXED, __HIP_MEMORY_SCOPE_AGENT);
}
// nonzero iff any 16-bit lane of q equals 0x7FFF (f16 NaN poison)
static __device__ __forceinline__ u64 swar_poison(u64 q) {
    u64 x = q ^ POISON;
    return (x - 0x0001000100010001ULL) & ~x & 0x8000800080008000ULL;
}
static __device__ __forceinline__ half8 h8(u64 lo, u64 hi) {
    union { u64 q[2]; half8 v; } u; u.q[0] = lo; u.q[1] = hi; return u.v;
}
static __device__ __forceinline__ half8 ld_h8(const f16* p) {
    return h8(ld64((const u64*)p), ld64((const u64*)p) == 0 ? ld64((const u64*)p + 1) : ld64((const u64*)p + 1));
}
// wave-parallel: flags[base..base+n) >= need
static __device__ __forceinline__ void pollA(const uint32_t* flags, int n,
                                             uint32_t need, int lane) {
    const uint32_t* p = flags + (size_t)(lane < n ? lane : 0) * FS;
    while (true) {
        uint32_t v = __hip_atomic_load(p, __ATOMIC_RELAXED, __HIP_MEMORY_SCOPE_AGENT);
        if (__all(v >= need)) break;
        __builtin_amdgcn_s_sleep(1);
    }
    __builtin_amdgcn_sched_barrier(0);
}

__global__ void __launch_bounds__(256, 1)
lstm_fused(const int* __restrict__ x, const float* __restrict__ emb,
           const float* __restrict__ w_ih0, const float* __restrict__ w_hh0,
           const float* __restrict__ b_ih0, const float* __restrict__ b_hh0,
           const float* __restrict__ w_ih1, const float* __restrict__ w_hh1,
           const float* __restrict__ b_ih1, const float* __restrict__ b_hh1,
           const float* __restrict__ fc_w, const float* __restrict__ fc_b,
           float* __restrict__ out, uint8_t* __restrict__ ws)
{
    const int wg   = blockIdx.x;
    const int tid  = threadIdx.x;
    const int lane = tid & 63;
    const int wave = tid >> 6;
    const int mtile = wave >> 1;       // batch half
    const int ntile = wave & 1;        // gate-col half
    const int r8   = lane & 15;
    const int kgb  = lane >> 4;
    const int arow = mtile * 16 + r8;
    const int tb = tid >> 3, tj = tid & 7;

    uint32_t* fA = (uint32_t*)(ws + OFF_FA);
    uint32_t* fB = (uint32_t*)(ws + OFF_FB);
    uint32_t* fP = (uint32_t*)(ws + OFF_FP);
    f16* h0buf = (f16*)(ws + WS_H0);
    f16* h1buf = (f16*)(ws + WS_H1);
    f16* ering = (f16*)(ws + WS_E);

    // ================= e-producer wgs (128..135) =================
    if (wg >= 128) {
        const int p = wg - 128;        // batch rows 4p..4p+3
        auto gather = [&](int t, int slot) {
#pragma unroll
            for (int rr = 0; rr < 2; ++rr) {
                int idx2 = rr * 256 + tid;
                if (idx2 < 384) {
                    int bl = idx2 / 96, seg = idx2 % 96, k0 = seg * 8;
                    int b = p * 4 + bl;
                    int tok = x[b * T_SEQ + t];
                    const float* src = emb + (size_t)tok * 768 + k0;
                    float4 v0 = ((const float4*)src)[0];
                    float4 v1 = ((const float4*)src)[1];
                    union { half8 h; u64 q[2]; } u;
                    u.h[0] = (f16)v0.x; u.h[1] = (f16)v0.y; u.h[2] = (f16)v0.z; u.h[3] = (f16)v0.w;
                    u.h[4] = (f16)v1.x; u.h[5] = (f16)v1.y; u.h[6] = (f16)v1.z; u.h[7] = (f16)v1.w;
                    u64* dst = (u64*)(ering + (size_t)slot * ESLOT + ((size_t)seg * 32 + b) * 8);
                    st64(dst, u.q[0]); st64(dst + 1, u.q[1]);
                }
            }
        };
        gather(0, 0); gather(1, 1); gather(2, 2);
        asm volatile("s_waitcnt vmcnt(0)" ::: "memory");
        __syncthreads();
        if (tid == 0) st32(fP + p * FS, 3u);
        for (int g = 3; g < T_SEQ; ++g) {
            pollA(fA, 64, (uint32_t)(g - 1), lane);   // L0 done step g-3 (slot g%3 free)
            gather(g, g % DE);
            asm volatile("s_waitcnt vmcnt(0)" ::: "memory");
            __syncthreads();
            if (tid == 0) st32(fP + p * FS, (uint32_t)(g + 1));
        }
        return;
    }

    // ================= recurrence wgs =================
    const bool isL0 = (wg < 64);
    const int wloc  = isL0 ? wg : wg - 64;
    const int j0    = wloc * 8;

    __shared__ half8 wlds[2 * 24 * 64];   // 48 KB: L0 e-part / L1 ih-part fragments
    __shared__ float accs[32][33];
    __shared__ float bias_lds[32];
    __shared__ f16   hsh[32][8];

    const int nrow = ((ntile * 2 + (r8 >> 3)) << 9) + j0 + (r8 & 7);
    const int NKW = isL0 ? 24 : 16;       // LDS-resident kc count per ntile

    // ---- LDS weights (waves 0,1 stage both ntile variants) ----
    if (wave < 2) {
        for (int kc = 0; kc < NKW; ++kc) {
            const float* src = isL0 ? (w_ih0 + (size_t)nrow * 768 + kc * 32 + kgb * 8)
                                    : (w_ih1 + (size_t)nrow * 512 + kc * 32 + kgb * 8);
            half8 v;
#pragma unroll
            for (int e = 0; e < 8; ++e) v[e] = (f16)src[e];
            wlds[((size_t)ntile * NKW + kc) * 64 + lane] = v;
        }
    }
    // ---- VGPR weights: W_hh part (16 frags) ----
    half8 breg[16];
    {
        const float* wsrc = isL0 ? w_hh0 : w_hh1;
#pragma unroll
        for (int kc = 0; kc < 16; ++kc) {
            const float* src = wsrc + (size_t)nrow * 512 + kc * 32 + kgb * 8;
            half8 v;
#pragma unroll
            for (int e = 0; e < 8; ++e) v[e] = (f16)src[e];
            breg[kc] = v;
        }
    }
    if (tid < 32) {
        int n2 = ((tid >> 3) << 9) + j0 + (tid & 7);
        bias_lds[tid] = isL0 ? (b_ih0[n2] + b_hh0[n2]) : (b_ih1[n2] + b_hh1[n2]);
    }

    // ---- init own slices: zero the h_{-1} plane, poison all others ----
    if (tid < 32) {
        const int ND = isL0 ? D0 : D1;
        f16* hb = isL0 ? h0buf : h1buf;
        for (int pl = 0; pl < ND; ++pl) {
            u64 v = (pl == ND - 1) ? 0ULL : POISON;   // h_{-1} lives in last plane
            u64* z = (u64*)(hb + (size_t)pl * HPLANE) + ((size_t)wloc * 32 + tid) * 2;
            st64(z, v); st64(z + 1, v);
        }
    }
    asm volatile("s_waitcnt vmcnt(0)" ::: "memory");
    __syncthreads();
    if (tid == 0) st32((isL0 ? fA : fB) + wloc * FS, isL0 ? 1u : 2u);
    // startup barrier: everyone's zeros/poison visible
    pollA(fA, 64, 1u, lane);
    pollA(fB, 64, 2u, lane);

    float cst = 0.f;
    const int crow0 = mtile * 16 + (lane >> 4) * 4;   // C/D: row=(lane>>4)*4+q
    const int ccol  = ntile * 16 + r8;                //      col=lane&15
    const half8* wb = wlds + (size_t)ntile * NKW * 64 + lane;

    if (isL0) {
        // =================== L0 ===================
        for (int s = 0; s < T_SEQ; ++s) {
            const u64* hp = (const u64*)(h0buf + (size_t)((s + D0 - 1) % D0) * HPLANE);
            u64 hq[32]; uint32_t fpv, fbv;
            auto loadA = [&]() {
#pragma unroll
                for (int kc = 0; kc < 16; ++kc) {
                    const u64* b = hp + ((size_t)(kc * 4 + kgb) * 32 + arow) * 2;
                    hq[2 * kc] = ld64(b); hq[2 * kc + 1] = ld64(b + 1);
                }
                fpv = ld32(fP + (lane & 7) * FS);
                fbv = ld32(fB + lane * FS);
            };
            loadA();
            while (true) {
                u64 bad = 0;
#pragma unroll
                for (int i = 0; i < 32; ++i) bad |= swar_poison(hq[i]);
                bool fail = (bad != 0) || ((lane < 8) && ((int)fpv < s + 1))
                            || ((int)fbv < s - 1);
                if (!__any(fail)) break;
                __builtin_amdgcn_s_sleep(1);
                loadA();
            }
            f32x4 acc0 = {0,0,0,0}, acc1 = {0,0,0,0};
#pragma unroll
            for (int kc = 0; kc < 16; ++kc) {        // W_hh0 x h0_{s-1} (validated)
                half8 a = h8(hq[2 * kc], hq[2 * kc + 1]);
                if (kc & 1) acc1 = __builtin_amdgcn_mfma_f32_16x16x32_f16(a, breg[kc], acc1, 0, 0, 0);
                else        acc0 = __builtin_amdgcn_mfma_f32_16x16x32_f16(a, breg[kc], acc0, 0, 0, 0);
            }
            const f16* pe = ering + (size_t)(s % DE) * ESLOT;
#pragma unroll
            for (int kc = 0; kc < 24; ++kc) {        // W_ih0 x e_s (fP-guarded)
                half8 a = ld_h8(pe + (((size_t)(kc * 4 + kgb) * 32 + arow) << 3));
                half8 bw = wb[kc * 64];
                if (kc & 1) acc1 = __builtin_amdgcn_mfma_f32_16x16x32_f16(a, bw, acc1, 0, 0, 0);
                else        acc0 = __builtin_amdgcn_mfma_f32_16x16x32_f16(a, bw, acc0, 0, 0, 0);
            }
            {
                f32x4 accv = acc0 + acc1;
#pragma unroll
                for (int q = 0; q < 4; ++q) accs[crow0 + q][ccol] = accv[q];
            }
            __syncthreads();
            {
                float gi = accs[tb][tj]      + bias_lds[tj];
                float gf = accs[tb][8 + tj]  + bias_lds[8 + tj];
                float gg = accs[tb][16 + tj] + bias_lds[16 + tj];
                float go = accs[tb][24 + tj] + bias_lds[24 + tj];
                float si = __builtin_amdgcn_rcpf(1.f + __expf(-gi));
                float sf = __builtin_amdgcn_rcpf(1.f + __expf(-gf));
                float so = __builtin_amdgcn_rcpf(1.f + __expf(-go));
                float tg = 1.f - 2.f * __builtin_amdgcn_rcpf(__expf(2.f * gg) + 1.f);
                cst = sf * cst + si * tg;
                float hv = so * (1.f - 2.f * __builtin_amdgcn_rcpf(__expf(2.f * cst) + 1.f));
                hsh[tb][tj] = (f16)hv;
            }
            __syncthreads();
            if (tid < 32) {                          // fire-and-forget publish + poison(2 ahead)
                u64* dst = (u64*)(h0buf + (size_t)(s % D0) * HPLANE) + ((size_t)wloc * 32 + tid) * 2;
                const u64* sp = (const u64*)hsh + tid * 2;
                st64(dst, sp[0]); st64(dst + 1, sp[1]);
                u64* pz = (u64*)(h0buf + (size_t)((s + 2) % D0) * HPLANE) + ((size_t)wloc * 32 + tid) * 2;
                st64(pz, POISON); st64(pz + 1, POISON);
            }
            if (tid == 0) st32(fA + wloc * FS, (uint32_t)(s + 2));   // for producers (lag 3)
        }
        return;
    }

    // =================== L1 ===================
    for (int s = 1; s <= T_SEQ; ++s) {
        const u64* p0 = (const u64*)(h0buf + (size_t)((s + D0 - 1) % D0) * HPLANE); // h0_{s-1}
        const u64* p1 = (const u64*)(h1buf + (size_t)((s + 2) & 3) * HPLANE);       // h1_{s-2}
        u64 q0[32], q1[32];
        auto loadB = [&]() {
#pragma unroll
            for (int kc = 0; kc < 16; ++kc) {
                const u64* a = p0 + ((size_t)(kc * 4 + kgb) * 32 + arow) * 2;
                const u64* b = p1 + ((size_t)(kc * 4 + kgb) * 32 + arow) * 2;
                q0[2 * kc] = ld64(a); q0[2 * kc + 1] = ld64(a + 1);
                q1[2 * kc] = ld64(b); q1[2 * kc + 1] = ld64(b + 1);
            }
        };
        loadB();
        while (true) {
            u64 bad = 0;
#pragma unroll
            for (int i = 0; i < 32; ++i) bad |= swar_poison(q0[i]) | swar_poison(q1[i]);
            if (!__any(bad != 0)) break;
            __builtin_amdgcn_s_sleep(1);
            loadB();
        }
        f32x4 acc0 = {0,0,0,0}, acc1 = {0,0,0,0};
#pragma unroll
        for (int kc = 0; kc < 16; ++kc) {            // W_ih1 x h0_{s-1} (LDS weights)
            half8 a = h8(q0[2 * kc], q0[2 * kc + 1]);
            half8 bw = wb[kc * 64];
            if (kc & 1) acc1 = __builtin_amdgcn_mfma_f32_16x16x32_f16(a, bw, acc1, 0, 0, 0);
            else        acc0 = __builtin_amdgcn_mfma_f32_16x16x32_f16(a, bw, acc0, 0, 0, 0);
        }
#pragma unroll
        for (int kc = 0; kc < 16; ++kc) {            // W_hh1 x h1_{s-2} (VGPR weights)
            half8 a = h8(q1[2 * kc], q1[2 * kc + 1]);
            if (kc & 1) acc1 = __builtin_amdgcn_mfma_f32_16x16x32_f16(a, breg[kc], acc1, 0, 0, 0);
            else        acc0 = __builtin_amdgcn_mfma_f32_16x16x32_f16(a, breg[kc], acc0, 0, 0, 0);
        }
        {
            f32x4 accv = acc0 + acc1;
#pragma unroll
            for (int q = 0; q < 4; ++q) accs[crow0 + q][ccol] = accv[q];
        }
        __syncthreads();
        {
            float gi = accs[tb][tj]      + bias_lds[tj];
            float gf = accs[tb][8 + tj]  + bias_lds[8 + tj];
            float gg = accs[tb][16 + tj] + bias_lds[16 + tj];
            float go = accs[tb][24 + tj] + bias_lds[24 + tj];
            float si = __builtin_amdgcn_rcpf(1.f + __expf(-gi));
            float sf = __builtin_amdgcn_rcpf(1.f + __expf(-gf));
            float so = __builtin_amdgcn_rcpf(1.f + __expf(-go));
            float tg = 1.f - 2.f * __builtin_amdgcn_rcpf(__expf(2.f * gg) + 1.f);
            cst = sf * cst + si * tg;
            float hv = so * (1.f - 2.f * __builtin_amdgcn_rcpf(__expf(2.f * cst) + 1.f));
            hsh[tb][tj] = (f16)hv;
        }
        __syncthreads();
        if (tid < 32) {
            u64* dst = (u64*)(h1buf + (size_t)((s + 3) & 3) * HPLANE) + ((size_t)wloc * 32 + tid) * 2;
            const u64* sp = (const u64*)hsh + tid * 2;
            st64(dst, sp[0]); st64(dst + 1, sp[1]);
            u64* pz = (u64*)(h1buf + (size_t)((s + 1) & 3) * HPLANE) + ((size_t)wloc * 32 + tid) * 2;
            st64(pz, POISON); st64(pz + 1, POISON);
        }
        if (tid == 0) st32(fB + wloc * FS, (uint32_t)(s + 2));       // L0 lag check (tol 3)
    }

    // ---------- FC epilogue (L1 wg 0): h2 = h1_{1023} = plane 3, validated ----------
    if (wloc == 0) {
        __syncthreads();
        const u64* h2g = (const u64*)(h1buf + (size_t)3 * HPLANE);
        u64* stg = (u64*)wlds;                       // reuse weight LDS
        for (int i = tid; i < 4096; i += 256) {
            u64 v = ld64(h2g + i);
            while (swar_poison(v)) { __builtin_amdgcn_s_sleep(1); v = ld64(h2g + i); }
            stg[i] = v;
        }
        __syncthreads();
        if (tid < 160) {
            int b = tid / 5, n = tid % 5;
            const f16* h2 = (const f16*)stg;
            float fsum = fc_b[n];
#pragma unroll 8
            for (int j = 0; j < 512; ++j)
                fsum += (float)h2[((j >> 3) * 32 + b) * 8 + (j & 7)] * fc_w[n * 512 + j];
            out[b * 5 + n] = fsum;
        }
    }
}

extern "C" void kernel_launch(void* const* d_in, const int* in_sizes, int n_in,
                              void* d_out, int out_size, void* d_ws, size_t ws_size,
                              hipStream_t stream) {
    (void)in_sizes; (void)n_in; (void)out_size; (void)ws_size;
    hipMemsetAsync(d_ws, 0, 8192, stream);   // flags start at 0
    lstm_fused<<<dim3(NWG), dim3(256), 0, stream>>>(
        (const int*)d_in[0],  (const float*)d_in[1],
        (const float*)d_in[2], (const float*)d_in[3],
        (const float*)d_in[4], (const float*)d_in[5],
        (const float*)d_in[6], (const float*)d_in[7],
        (const float*)d_in[8], (const float*)d_in[9],
        (const float*)d_in[10], (const float*)d_in[11],
        (float*)d_out, (uint8_t*)d_ws);
}